// Round 12
// baseline (3840.882 us; speedup 1.0000x reference)
//
#include <hip/hip_runtime.h>
#include <math.h>

typedef float f4 __attribute__((ext_vector_type(4)));
typedef short short8 __attribute__((ext_vector_type(8)));
typedef unsigned short us4 __attribute__((ext_vector_type(4)));

#define DEV static __device__ __forceinline__
#define AGENT __HIP_MEMORY_SCOPE_AGENT

DEV float bf2f(unsigned short u){ unsigned int x=((unsigned int)u)<<16; float f; __builtin_memcpy(&f,&x,4); return f; }
DEV unsigned short f2bf(float f){ unsigned int x; __builtin_memcpy(&x,&f,4); return (unsigned short)((x + 0x7fffu + ((x>>16)&1u))>>16); }

struct bfpair { short hi, lo; };
DEV bfpair splitbf(float v){
  bfpair p;
  unsigned short h_ = f2bf(v);
  p.hi = (short)h_;
  p.lo = (short)f2bf(v - bf2f(h_));
  return p;
}

DEV unsigned long long ldA64(const void* p){
  return __hip_atomic_load((const unsigned long long*)p, __ATOMIC_RELAXED, AGENT);
}
DEV void stA64(void* p, unsigned long long v){
  __hip_atomic_store((unsigned long long*)p, v, __ATOMIC_RELAXED, AGENT);
}
DEV void f2of(unsigned long long q, float* f0, float* f1){
  unsigned int lo=(unsigned int)q, hi=(unsigned int)(q>>32);
  __builtin_memcpy(f0,&lo,4); __builtin_memcpy(f1,&hi,4);
}
DEV unsigned long long packf2(float a, float b){
  unsigned int ua, ub; __builtin_memcpy(&ua,&a,4); __builtin_memcpy(&ub,&b,4);
  return (unsigned long long)ua | ((unsigned long long)ub << 32);
}

// ---- wide device-coherent loads/stores (bypass L2) ----
DEV void ld1x16_sc(const void* p, f4* o){
  asm volatile(
    "global_load_dwordx4 %0, %1, off sc0 sc1\n\t"
    "s_waitcnt vmcnt(0)"
    : "=&v"(o[0]) : "v"(p) : "memory");
}
DEV void ld8x16_sc(const void* p, f4* o){
  asm volatile(
    "global_load_dwordx4 %0, %8, off sc0 sc1\n\t"
    "global_load_dwordx4 %1, %8, off offset:16 sc0 sc1\n\t"
    "global_load_dwordx4 %2, %8, off offset:32 sc0 sc1\n\t"
    "global_load_dwordx4 %3, %8, off offset:48 sc0 sc1\n\t"
    "global_load_dwordx4 %4, %8, off offset:64 sc0 sc1\n\t"
    "global_load_dwordx4 %5, %8, off offset:80 sc0 sc1\n\t"
    "global_load_dwordx4 %6, %8, off offset:96 sc0 sc1\n\t"
    "global_load_dwordx4 %7, %8, off offset:112 sc0 sc1\n\t"
    "s_waitcnt vmcnt(0)"
    : "=&v"(o[0]),"=&v"(o[1]),"=&v"(o[2]),"=&v"(o[3]),
      "=&v"(o[4]),"=&v"(o[5]),"=&v"(o[6]),"=&v"(o[7])
    : "v"(p) : "memory");
}
DEV void st8x16_sc(void* p, const f4* v){
  asm volatile(
    "global_store_dwordx4 %8, %0, off sc0 sc1\n\t"
    "global_store_dwordx4 %8, %1, off offset:16 sc0 sc1\n\t"
    "global_store_dwordx4 %8, %2, off offset:32 sc0 sc1\n\t"
    "global_store_dwordx4 %8, %3, off offset:48 sc0 sc1\n\t"
    "global_store_dwordx4 %8, %4, off offset:64 sc0 sc1\n\t"
    "global_store_dwordx4 %8, %5, off offset:80 sc0 sc1\n\t"
    "global_store_dwordx4 %8, %6, off offset:96 sc0 sc1\n\t"
    "global_store_dwordx4 %8, %7, off offset:112 sc0 sc1\n\t"
    "s_waitcnt vmcnt(0)"
    :: "v"(v[0]),"v"(v[1]),"v"(v[2]),"v"(v[3]),
       "v"(v[4]),"v"(v[5]),"v"(v[6]),"v"(v[7]),"v"(p) : "memory");
}

// LDS addressing with XOR swizzle on 16B chunks
DEV int lds_off(int row,int strideShorts,int kShort){
  return row*strideShorts*2 + ((((kShort & ~7)*2) ^ ((row & 7)<<4)) + (kShort & 7)*2);
}
DEV void st8(unsigned short* lds,int row,int strideShorts,int k0,short8 v){
  *(short8*)((char*)lds + lds_off(row,strideShorts,k0)) = v;
}
DEV short8 ldfrag(const unsigned short* lds,int rowBase,int strideShorts,int k0){
  int lane = (int)(threadIdx.x & 63u);
  int row = rowBase + (lane & 15);
  int k = k0 + (lane >> 4)*8;
  return *(const short8*)((const char*)lds + lds_off(row,strideShorts,k));
}

DEV float dot8(f4 a0, f4 a1, short8 w){
  return a0[0]*bf2f((unsigned short)w[0]) + a0[1]*bf2f((unsigned short)w[1])
       + a0[2]*bf2f((unsigned short)w[2]) + a0[3]*bf2f((unsigned short)w[3])
       + a1[0]*bf2f((unsigned short)w[4]) + a1[1]*bf2f((unsigned short)w[5])
       + a1[2]*bf2f((unsigned short)w[6]) + a1[3]*bf2f((unsigned short)w[7]);
}

// enc barrier: slot-per-generation (8 WGs, low contention)
DEV void gbar_slot(int* slot, int nwg){
  __syncthreads();
  if (threadIdx.x==0){
    __hip_atomic_fetch_add(slot,1,__ATOMIC_RELAXED,AGENT);
    while (__hip_atomic_load(slot,__ATOMIC_RELAXED,AGENT) < nwg){
      __builtin_amdgcn_s_sleep(2);
    }
  }
  __syncthreads();
}

// dec barrier: per-WG counters on separate cachelines
DEV void dbar(int* ctrs, int wg, int target){
  __syncthreads();
  if (threadIdx.x < 64){
    if (threadIdx.x == 0)
      __hip_atomic_store(&ctrs[wg*32], target, __ATOMIC_RELAXED, AGENT);
    for(;;){
      int v = __hip_atomic_load(&ctrs[(int)threadIdx.x*32], __ATOMIC_RELAXED, AGENT);
      if (__all(v >= target)) break;
      __builtin_amdgcn_s_sleep(2);
    }
  }
  __syncthreads();
}
DEV void vwait(int* ctrs, int target){
  if (threadIdx.x < 64){
    for(;;){
      int v = __hip_atomic_load(&ctrs[(int)threadIdx.x*32], __ATOMIC_RELAXED, AGENT);
      if (__all(v >= target)) break;
      __builtin_amdgcn_s_sleep(64);
    }
  }
  __syncthreads();
}
DEV void cwait(int* cctrs, int target){
  if (threadIdx.x < 64){
    for(;;){
      int v = __hip_atomic_load(&cctrs[((int)threadIdx.x & 7)*32], __ATOMIC_RELAXED, AGENT);
      if (__all(v >= target)) break;
      __builtin_amdgcn_s_sleep(64);
    }
  }
  __syncthreads();
}

__global__ void cvt_kernel(const float* __restrict__ src, unsigned short* __restrict__ dst, int n4){
  int stride = gridDim.x*blockDim.x;
  for (long i = blockIdx.x*blockDim.x + threadIdx.x; i < n4; i += stride){
    f4 v = *(const f4*)(src + i*4);
    us4 o; o[0]=f2bf(v[0]); o[1]=f2bf(v[1]); o[2]=f2bf(v[2]); o[3]=f2bf(v[3]);
    *(us4*)(dst + i*4) = o;
  }
}

__global__ void embed_kernel(const int* __restrict__ nx, const int* __restrict__ x,
  const int* __restrict__ label, const float* __restrict__ tok,
  const float* __restrict__ start, const float* __restrict__ style,
  unsigned short* __restrict__ embE, unsigned short* __restrict__ embD,
  float* __restrict__ h0)
{
  const int half = 4096*32;
  int i = blockIdx.x*256 + threadIdx.x;
  if (i < 2*half){
    const bool dec = i >= half;
    int j = dec ? i - half : i;
    int m = j >> 5, c4 = j & 31;
    int b = m & 31, tt = m >> 5;
    const float* src;
    if (!dec) src = tok + (long)nx[b*128 + tt]*128;
    else src = (tt == 0) ? start : (tok + (long)x[b*128 + tt - 1]*128);
    f4 v = *(const f4*)(src + c4*4);
    us4 o; o[0]=f2bf(v[0]); o[1]=f2bf(v[1]); o[2]=f2bf(v[2]); o[3]=f2bf(v[3]);
    *(us4*)((dec ? embD : embE) + (long)m*128 + c4*4) = o;
  } else {
    int j = i - 2*half;
    if (j < 4096){
      int b = j >> 7, c4 = j & 127;
      *(f4*)(h0 + b*512 + c4*4) = *(const f4*)(style + (long)label[b]*512 + c4*4);
    }
  }
}

__global__ void kv_reshape(const float* __restrict__ kvp, unsigned short* __restrict__ Kb, unsigned short* __restrict__ Vb){
  long i = (long)blockIdx.x*256 + threadIdx.x;
  if (i >= (long)4096*1024) return;
  int m = (int)(i >> 10), n = (int)(i & 1023);
  int s = m >> 5, b = m & 31;
  unsigned short bv = f2bf(kvp[i]);
  if (n < 512){
    int hh = n >> 6, d = n & 63;
    Kb[((long)(b*8 + hh)*128 + s)*64 + d] = bv;
  } else {
    int n2 = n - 512; int hh = n2 >> 6, d = n2 & 63;
    Vb[((long)(b*8 + hh)*64 + d)*128 + s] = bv;
  }
}

// Generic 64x64 bf16-MFMA GEMM (MODE 0: A bf16; MODE 1: A=concat f32 K=512)
template<int MODE>
__global__ __launch_bounds__(256,2) void gemm64(
  const unsigned short* __restrict__ Bw, const float* __restrict__ bias,
  float* __restrict__ C, int M, int N, int K, int ldC,
  const unsigned short* __restrict__ Abf,
  const float* __restrict__ Af0, const float* __restrict__ Af1)
{
  __shared__ unsigned short a_s[64*64];
  __shared__ unsigned short b_s[64*64];
  const int tid = threadIdx.x, lane = tid & 63, wv = tid >> 6;
  const long mb = (long)blockIdx.x*64, nb = (long)blockIdx.y*64;
  f4 z = {0.f,0.f,0.f,0.f};
  f4 acc[4] = {z,z,z,z};
  const int r = tid >> 2, q = tid & 3, k0 = q*16;
  for (int kb = 0; kb < K; kb += 64){
    if (MODE==0){
      const unsigned short* src = Abf + (mb + r)*K + kb + k0;
      st8(a_s, r, 64, k0,   *(const short8*)src);
      st8(a_s, r, 64, k0+8, *(const short8*)(src+8));
    } else {
      float tmp[16];
      long m = mb + r;
      int kg = kb + k0;
      const float* base = (kg < 256) ? (Af0 + m*256 + kg) : (Af1 + m*256 + (kg - 256));
      #pragma unroll
      for (int i=0;i<16;i++) tmp[i] = base[i];
      short8 v0, v1;
      #pragma unroll
      for (int i=0;i<8;i++){ v0[i] = (short)f2bf(tmp[i]); v1[i] = (short)f2bf(tmp[8+i]); }
      st8(a_s, r, 64, k0, v0); st8(a_s, r, 64, k0+8, v1);
    }
    {
      const unsigned short* src = Bw + (nb + r)*K + kb + k0;
      st8(b_s, r, 64, k0,   *(const short8*)src);
      st8(b_s, r, 64, k0+8, *(const short8*)(src+8));
    }
    __syncthreads();
    #pragma unroll
    for (int kf=0; kf<2; kf++){
      short8 bfr = ldfrag(b_s, wv*16, 64, kf*32);
      #pragma unroll
      for (int mt=0; mt<4; mt++){
        short8 afr = ldfrag(a_s, mt*16, 64, kf*32);
        acc[mt] = __builtin_amdgcn_mfma_f32_16x16x32_bf16(afr, bfr, acc[mt], 0,0,0);
      }
    }
    __syncthreads();
  }
  const long col = nb + wv*16 + (lane & 15);
  const float bs = bias[col];
  #pragma unroll
  for (int mt=0; mt<4; mt++){
    #pragma unroll
    for (int rr=0; rr<4; rr++){
      long row = mb + mt*16 + (lane>>4)*4 + rr;
      C[row*(long)ldC + col] = acc[mt][rr] + bs;
    }
  }
}

// Bidirectional GRU encoder — wide sc loads for h stage-in, packed 8B h ping-pong
__global__ __launch_bounds__(384) void enc_kernel(
  const float* __restrict__ WhhF_f, const float* __restrict__ WhhB_f,
  const float* __restrict__ GIF, const float* __restrict__ GIB,
  const float* __restrict__ bhhF, const float* __restrict__ bhhB,
  float* __restrict__ OUTF, float* __restrict__ OUTB,
  float* __restrict__ Hf,
  int* bar)
{
  __shared__ unsigned short whh_hi[96*256];
  __shared__ unsigned short whh_lo[96*256];
  __shared__ unsigned short a_hi[32*256];
  __shared__ unsigned short a_lo[32*256];
  __shared__ float ghscr[32*96];
  const int tid = threadIdx.x;
  const int wg = blockIdx.x;
  const int dir = wg >> 3, wgl = wg & 7;
  const float* Whh_f = dir ? WhhB_f : WhhF_f;
  const float* GI = dir ? GIB : GIF;
  const float* bhh = dir ? bhhB : bhhF;
  float* OUT = dir ? OUTB : OUTF;

  for (int idx = tid; idx < 96*32; idx += 384){
    int lr = idx >> 5, ch = idx & 31;
    int g_ = lr >> 5, jj = lr & 31;
    const float* wsrc = Whh_f + (long)(g_*256 + wgl*32 + jj)*256 + ch*8;
    short8 vh, vl;
    #pragma unroll
    for (int i=0;i<8;i++){ bfpair p = splitbf(wsrc[i]); vh[i] = p.hi; vl[i] = p.lo; }
    st8(whh_hi, lr, 256, ch*8, vh);
    st8(whh_lo, lr, 256, ch*8, vl);
  }
  __syncthreads();
  for (int t = 0; t < 128; t++){
    const int s = dir ? (127 - t) : t;
    const float* hbr = Hf + ((size_t)((t&1)*2 + dir))*(32*256);
    float* hbw = Hf + ((size_t)(((t+1)&1)*2 + dir))*(32*256);
    if (tid < 256){
      int b = tid >> 3, kg = tid & 7;
      f4 hv[8];
      ld8x16_sc(hbr + b*256 + kg*32, hv);
      #pragma unroll
      for (int c=0;c<4;c++){
        short8 vh, vl;
        #pragma unroll
        for (int e=0;e<8;e++){
          float f = hv[c*2 + (e>>2)][e&3];
          bfpair p = splitbf(f);
          vh[e] = p.hi; vl[e] = p.lo;
        }
        st8(a_hi, b, 256, kg*32 + c*8, vh);
        st8(a_lo, b, 256, kg*32 + c*8, vl);
      }
    }
    __syncthreads();
    {
      const int wv = tid >> 6;
      f4 acc0 = {0.f,0.f,0.f,0.f}, acc1 = {0.f,0.f,0.f,0.f};
      #pragma unroll
      for (int kf=0; kf<8; kf++){
        short8 bhi = ldfrag(whh_hi, wv*16, 256, kf*32);
        short8 blo = ldfrag(whh_lo, wv*16, 256, kf*32);
        short8 ah0 = ldfrag(a_hi, 0, 256, kf*32);
        short8 al0 = ldfrag(a_lo, 0, 256, kf*32);
        short8 ah1 = ldfrag(a_hi, 16, 256, kf*32);
        short8 al1 = ldfrag(a_lo, 16, 256, kf*32);
        acc0 = __builtin_amdgcn_mfma_f32_16x16x32_bf16(ah0, bhi, acc0, 0,0,0);
        acc0 = __builtin_amdgcn_mfma_f32_16x16x32_bf16(al0, bhi, acc0, 0,0,0);
        acc0 = __builtin_amdgcn_mfma_f32_16x16x32_bf16(ah0, blo, acc0, 0,0,0);
        acc1 = __builtin_amdgcn_mfma_f32_16x16x32_bf16(ah1, bhi, acc1, 0,0,0);
        acc1 = __builtin_amdgcn_mfma_f32_16x16x32_bf16(al1, bhi, acc1, 0,0,0);
        acc1 = __builtin_amdgcn_mfma_f32_16x16x32_bf16(ah1, blo, acc1, 0,0,0);
      }
      const int lane = tid & 63;
      const int cl = wv*16 + (lane & 15);
      #pragma unroll
      for (int rr=0; rr<4; rr++){
        int r0 = (lane>>4)*4 + rr;
        ghscr[r0*96 + cl] = acc0[rr];
        ghscr[(16+r0)*96 + cl] = acc1[rr];
      }
    }
    __syncthreads();
    for (int task = tid; task < 512; task += 384){
      int b = task >> 4, pj = task & 15;
      int jj0 = pj*2;
      int jg0 = wgl*32 + jj0;
      const float* gi = GI + ((long)s*32 + b)*768;
      unsigned long long hq = ldA64(hbr + b*256 + jg0);
      float hp0, hp1; f2of(hq, &hp0, &hp1);
      float hn01[2];
      #pragma unroll
      for (int e=0;e<2;e++){
        int jj = jj0 + e, jg = jg0 + e;
        float ghr = ghscr[b*96 + jj]      + bhh[jg];
        float ghz = ghscr[b*96 + 32 + jj] + bhh[256 + jg];
        float ghn = ghscr[b*96 + 64 + jj] + bhh[512 + jg];
        float r_ = 1.f/(1.f + __expf(-(gi[jg] + ghr)));
        float z_ = 1.f/(1.f + __expf(-(gi[256+jg] + ghz)));
        float n_ = tanhf(gi[512+jg] + r_*ghn);
        float hp = e ? hp1 : hp0;
        hn01[e] = (1.f - z_)*n_ + z_*hp;
      }
      *(unsigned long long*)(&OUT[((long)s*32 + b)*256 + jg0]) = packf2(hn01[0], hn01[1]);
      stA64(hbw + b*256 + jg0, packf2(hn01[0], hn01[1]));
    }
    gbar_slot(bar + dir*128 + t, 8);
  }
}

// ---------------- fused decoder + converters + vocab-projection ----------------
struct DecS {
  unsigned short whh_hi[32*512];
  unsigned short whh_lo[32*512];
  unsigned short a_hi[32*512];
  unsigned short a_lo[32*512];
  float scr[32*64];
  float attn_l[4*128];
  float ctxs[4*64];
  float redm[32*8*2];
  float murs[64];
  float hnfr[32*8];
  float lngl[512], lnbl[512];
  float s1l[24], s2l[24];
};
struct VocS {
  unsigned short a_s[128*512];
  unsigned short b_s[64*64];
  float gl[512];
  float s2g[256];
};
struct CvtS {
  float redm[32*8*2];
  float murs[64];
};
union SU { DecS d; VocS v; CvtS c; };

__global__ __launch_bounds__(256,1) void dec_fused(
  const float* __restrict__ Whh_f,
  const unsigned short* __restrict__ WqBf,
  const unsigned short* __restrict__ Wout,
  const unsigned short* __restrict__ Kbf,
  const unsigned short* __restrict__ Vbf,
  const float* __restrict__ GI,
  const float* __restrict__ bhh,
  const float* __restrict__ aib,
  const float* __restrict__ aob,
  const float* __restrict__ lng,
  const float* __restrict__ lnb,
  const float* __restrict__ h0,
  float* __restrict__ Y,
  unsigned int* __restrict__ hdec32,
  unsigned short* __restrict__ Ybf,
  const unsigned short* __restrict__ Pbf,
  const float* __restrict__ projWf,
  const float* __restrict__ projB,
  float* __restrict__ out,
  int* ctrs)
{
  __shared__ SU s;
  const int tid = threadIdx.x;
  const int lane = tid & 63, wv = tid >> 6;
  int* cctrs = ctrs + 2048;   // converter lines: bytes [8192, 9216)

  if (blockIdx.x < 64){
    // ================= DECODER =================
    const int wg = blockIdx.x;
    const int h = wg >> 3, bg = wg & 7;
    const int jbase = wg*8;
    const int cw = wg & 7;

    if (tid < 24){ s.d.s1l[tid] = 0.f; s.d.s2l[tid] = 0.f; }
    __syncthreads();
    for (int idx = tid; idx < 32*64; idx += 256){
      int lr = idx >> 6, ch = idx & 63;
      short8 vh = {0,0,0,0,0,0,0,0}, vl = {0,0,0,0,0,0,0,0};
      if (lr < 24){
        int g_ = lr >> 3, jj = lr & 7;
        const float* wsrc = Whh_f + (long)(g_*512 + jbase + jj)*512 + ch*8;
        float s1p = 0.f, s2p = 0.f;
        #pragma unroll
        for (int i=0;i<8;i++){
          float wvv = wsrc[i];
          float gv = lng[ch*8+i];
          float bv = lnb[ch*8+i];
          float wp = wvv*gv;
          bfpair p = splitbf(wp);
          vh[i] = p.hi; vl[i] = p.lo;
          s1p += wp; s2p += bv*wvv;
        }
        atomicAdd(&s.d.s1l[lr], s1p);
        atomicAdd(&s.d.s2l[lr], s2p);
      }
      st8(s.d.whh_hi, lr, 512, ch*8, vh);
      st8(s.d.whh_lo, lr, 512, ch*8, vl);
    }
    for (int i = tid; i < 512; i += 256){ s.d.lngl[i] = lng[i]; s.d.lnbl[i] = lnb[i]; }

    const int qrow = h*64 + wv*16 + (lane & 15);
    const int kb0q = (lane>>4)*8;
    const unsigned short* wqbase = WqBf + (long)qrow*512 + kb0q;
    const int b_l = wv;
    const int bglob = bg*4 + b_l;
    const unsigned short* kbase = Kbf + ((long)(bglob*8 + h)*128 + lane*2)*64;
    const unsigned short* vbase = Vbf + ((long)(bglob*8 + h)*64 + lane)*128;
    const int jp = tid & 127;
    const unsigned short* wobase = Wout + (long)(jp*4)*512 + h*64;
    const float qb = aib[h*64 + wv*16 + (lane & 15)];
    const int bA = tid >> 3, kgA = tid & 7;
    const int jjA = tid & 7;
    const int jgA = jbase + jjA;
    const float bhr = bhh[jgA], bhz = bhh[512 + jgA], bhn = bhh[1024 + jgA];
    const float aobv = aob[jgA];
    __syncthreads();

    int lgen = 0;
    float gir = GI[((long)0*32 + bA)*1536 + jgA];
    float giz = GI[((long)0*32 + bA)*1536 + 512 + jgA];
    float gin = GI[((long)0*32 + bA)*1536 + 1024 + jgA];
    for (int t = 0; t < 128; t++){
      // ---- STAGE A ----
      if (t == 0){
        const float* src = h0 + bA*512 + kgA*64;
        #pragma unroll
        for (int c=0;c<8;c++){
          short8 vh, vl;
          #pragma unroll
          for (int i=0;i<8;i++){
            float v = src[c*8+i];
            float gv = s.d.lngl[kgA*64 + c*8 + i];
            bfpair p = splitbf(v/gv);
            vh[i] = p.hi; vl[i] = p.lo;
            if (kgA == h && c == cw) s.d.hnfr[bA*8+i] = v;
          }
          st8(s.d.a_hi, bA, 512, kgA*64 + c*8, vh);
          st8(s.d.a_lo, bA, 512, kgA*64 + c*8, vl);
        }
        __syncthreads();
      } else {
        // normal cached loads: Y addresses are write-once per dispatch; L2 fill
        // is shared by the ~8 dec WGs on each XCD (broadcast via L2, not MALL)
        f4 yv[16];
        const f4* ys = (const f4*)(Y + ((long)(t-1)*32 + bA)*512 + kgA*64);
        #pragma unroll
        for (int i=0;i<16;i++) yv[i] = ys[i];
        float sm = 0.f, sq = 0.f;
        #pragma unroll
        for (int c=0;c<8;c++){
          short8 vh, vl;
          #pragma unroll
          for (int e=0;e<8;e++){
            float f = yv[c*2 + (e>>2)][e&3];
            sm += f; sq += f*f;
            bfpair p = splitbf(f);
            vh[e] = p.hi; vl[e] = p.lo;
            if (kgA == h && c == cw) s.d.hnfr[bA*8+e] = f;
          }
          st8(s.d.a_hi, bA, 512, kgA*64 + c*8, vh);
          st8(s.d.a_lo, bA, 512, kgA*64 + c*8, vl);
        }
        s.d.redm[(bA*8+kgA)*2] = sm; s.d.redm[(bA*8+kgA)*2+1] = sq;
        __syncthreads();
        if (tid < 32){
          float S1=0.f, S2=0.f;
          #pragma unroll
          for (int i=0;i<8;i++){ S1 += s.d.redm[(tid*8+i)*2]; S2 += s.d.redm[(tid*8+i)*2+1]; }
          float mu = S1*(1.f/512.f);
          float var = S2*(1.f/512.f) - mu*mu;
          s.d.murs[tid*2] = mu; s.d.murs[tid*2+1] = rsqrtf(var + 1e-5f);
        }
        __syncthreads();
      }
      {
        const int mt = wv >> 1, nt = wv & 1;
        f4 acc = {0.f,0.f,0.f,0.f};
        #pragma unroll
        for (int kf=0; kf<16; kf++){
          short8 bhi = ldfrag(s.d.whh_hi, nt*16, 512, kf*32);
          short8 blo = ldfrag(s.d.whh_lo, nt*16, 512, kf*32);
          short8 ahi = ldfrag(s.d.a_hi, mt*16, 512, kf*32);
          short8 alo = ldfrag(s.d.a_lo, mt*16, 512, kf*32);
          acc = __builtin_amdgcn_mfma_f32_16x16x32_bf16(ahi, bhi, acc, 0,0,0);
          acc = __builtin_amdgcn_mfma_f32_16x16x32_bf16(alo, bhi, acc, 0,0,0);
          acc = __builtin_amdgcn_mfma_f32_16x16x32_bf16(ahi, blo, acc, 0,0,0);
        }
        const int cl = nt*16 + (lane & 15);
        if (cl < 24){
          #pragma unroll
          for (int rr=0; rr<4; rr++){
            int row = mt*16 + (lane>>4)*4 + rr;
            s.d.scr[row*32 + cl] = acc[rr];
          }
        }
      }
      __syncthreads();
      {
        const float mu = t ? s.d.murs[bA*2] : 0.f;
        const float rsv = t ? s.d.murs[bA*2+1] : 1.f;
        const float c2 = rsv*mu;
        float ghr = rsv*s.d.scr[bA*32 + jjA]      - c2*s.d.s1l[jjA]      + (t ? s.d.s2l[jjA]      : 0.f) + bhr;
        float ghz = rsv*s.d.scr[bA*32 + 8 + jjA]  - c2*s.d.s1l[8 + jjA]  + (t ? s.d.s2l[8 + jjA]  : 0.f) + bhz;
        float ghn = rsv*s.d.scr[bA*32 + 16 + jjA] - c2*s.d.s1l[16 + jjA] + (t ? s.d.s2l[16 + jjA] : 0.f) + bhn;
        float r_ = 1.f/(1.f + __expf(-(gir + ghr)));
        float z_ = 1.f/(1.f + __expf(-(giz + ghz)));
        float n_ = tanhf(gin + r_*ghn);
        float hpv = s.d.hnfr[bA*8 + jjA];
        float hp = t ? (hpv - mu)*rsv*s.d.lngl[jgA] + s.d.lnbl[jgA] : hpv;
        float hd = (1.f - z_)*n_ + z_*hp;
        unsigned int hb = (unsigned int)f2bf(hd);
        unsigned int other = (unsigned int)__shfl_xor((int)hb, 1);
        if ((jjA & 1) == 0){
          unsigned int pack = hb | (other << 16);
          __hip_atomic_store(&hdec32[bA*256 + (jgA >> 1)], pack, __ATOMIC_RELAXED, AGENT);
        }
        __hip_atomic_store(&Y[((long)t*32 + bA)*512 + jgA], hd + aobv, __ATOMIC_RELAXED, AGENT);
      }
      dbar(ctrs, wg, ++lgen);
      // ---- STAGE B: stage only this WG's 4 batch rows of hdec (sc: addresses repeat) ----
      {
        const int r4 = tid >> 6, ch = tid & 63;
        f4 hv;
        ld1x16_sc(hdec32 + (bg*4 + r4)*256 + ch*4, &hv);
        short8 v;
        #pragma unroll
        for (int w2=0; w2<4; w2++){
          float fv = hv[w2];
          unsigned int u; __builtin_memcpy(&u, &fv, 4);
          v[w2*2]   = (short)(u & 0xffff);
          v[w2*2+1] = (short)(u >> 16);
        }
        st8(s.d.a_hi, r4, 512, ch*8, v);
      }
      __syncthreads();
      {
        f4 acc0 = {0.f,0.f,0.f,0.f};
        #pragma unroll
        for (int kf=0; kf<16; kf++){
          short8 bfr = *(const short8*)(wqbase + kf*32);
          acc0 = __builtin_amdgcn_mfma_f32_16x16x32_bf16(ldfrag(s.d.a_hi, 0, 512, kf*32), bfr, acc0, 0,0,0);
        }
        const int cl = wv*16 + (lane & 15);
        if ((lane >> 4) == 0){
          #pragma unroll
          for (int rr=0; rr<4; rr++)
            s.d.scr[rr*64 + cl] = acc0[rr] + qb;
        }
      }
      __syncthreads();
      {
        const f4* qp = (const f4*)(s.d.scr + b_l*64);
        float s0 = 0.f, s1 = 0.f;
        #pragma unroll
        for (int c=0;c<8;c++) s0 += dot8(qp[c*2], qp[c*2+1], *(const short8*)(kbase + c*8));
        #pragma unroll
        for (int c=0;c<8;c++) s1 += dot8(qp[c*2], qp[c*2+1], *(const short8*)(kbase + 64 + c*8));
        s0 *= 0.125f; s1 *= 0.125f;
        float mx = fmaxf(s0, s1);
        #pragma unroll
        for (int o=1;o<64;o<<=1) mx = fmaxf(mx, __shfl_xor(mx, o));
        float e0 = __expf(s0 - mx), e1 = __expf(s1 - mx);
        float sm = e0 + e1;
        #pragma unroll
        for (int o=1;o<64;o<<=1) sm += __shfl_xor(sm, o);
        float inv = 1.f/sm;
        s.d.attn_l[b_l*128 + lane*2]   = e0*inv;
        s.d.attn_l[b_l*128 + lane*2+1] = e1*inv;
      }
      __syncthreads();
      {
        const f4* ap = (const f4*)(s.d.attn_l + b_l*128);
        float cx = 0.f;
        #pragma unroll
        for (int c=0;c<16;c++) cx += dot8(ap[c*2], ap[c*2+1], *(const short8*)(vbase + c*8));
        s.d.ctxs[b_l*64 + lane] = cx;
      }
      __syncthreads();
      {
        const int b2 = tid >> 7;
        #pragma unroll
        for (int jj=0;jj<4;jj++){
          const unsigned short* wb = wobase + (long)jj*512;
          short8 w0 = *(const short8*)(wb);
          short8 w1 = *(const short8*)(wb+8);
          short8 w2 = *(const short8*)(wb+16);
          short8 w3 = *(const short8*)(wb+24);
          short8 w4 = *(const short8*)(wb+32);
          short8 w5 = *(const short8*)(wb+40);
          short8 w6 = *(const short8*)(wb+48);
          short8 w7 = *(const short8*)(wb+56);
          #pragma unroll
          for (int bb=0; bb<2; bb++){
            const int bl = b2 + bb*2;
            const int bgl = bg*4 + bl;
            const f4* cp = (const f4*)(s.d.ctxs + bl*64);
            float cj = dot8(cp[0], cp[1], w0) + dot8(cp[2], cp[3], w1)
                     + dot8(cp[4], cp[5], w2) + dot8(cp[6], cp[7], w3)
                     + dot8(cp[8], cp[9], w4) + dot8(cp[10], cp[11], w5)
                     + dot8(cp[12], cp[13], w6) + dot8(cp[14], cp[15], w7);
            atomicAdd(&Y[((long)t*32 + bgl)*512 + jp*4 + jj], cj);
          }
        }
      }
      if (t < 127){
        long base = ((long)(t+1)*32 + bA)*1536 + jgA;
        gir = GI[base];
        giz = GI[base + 512];
        gin = GI[base + 1024];
      }
      dbar(ctrs, wg, ++lgen);
    }
  } else if (blockIdx.x < 72){
    // ================= CONVERTERS: Y chunk -> LN'd bf16 Ybf =================
    const int w = blockIdx.x - 64;
    const int rr = tid >> 3, seg = tid & 7;
    for (int c = 0; c < 16; c++){
      vwait(ctrs, 16*(c+1));
      long m = (long)c*256 + w*32 + rr;
      f4 yv[16];
      const f4* ys = (const f4*)(Y + m*512 + seg*64);
      #pragma unroll
      for (int i=0;i<16;i++) yv[i] = ys[i];
      float sm = 0.f, sq = 0.f;
      #pragma unroll
      for (int i=0;i<16;i++){
        f4 v = yv[i];
        sm += v[0]+v[1]+v[2]+v[3];
        sq += v[0]*v[0]+v[1]*v[1]+v[2]*v[2]+v[3]*v[3];
      }
      s.c.redm[(rr*8+seg)*2] = sm; s.c.redm[(rr*8+seg)*2+1] = sq;
      __syncthreads();
      if (tid < 32){
        float S1=0.f, S2=0.f;
        #pragma unroll
        for (int i=0;i<8;i++){ S1 += s.c.redm[(tid*8+i)*2]; S2 += s.c.redm[(tid*8+i)*2+1]; }
        float mu = S1*(1.f/512.f);
        float var = S2*(1.f/512.f) - mu*mu;
        s.c.murs[tid*2] = mu; s.c.murs[tid*2+1] = rsqrtf(var + 1e-5f);
      }
      __syncthreads();
      const float mu = s.c.murs[rr*2], rsv = s.c.murs[rr*2+1];
      f4 ob[8];
      #pragma unroll
      for (int i2=0;i2<32;i2++){
        float a0 = (yv[(2*i2)>>2][(2*i2)&3] - mu)*rsv;
        float a1v = (yv[(2*i2+1)>>2][(2*i2+1)&3] - mu)*rsv;
        unsigned int u = (unsigned int)f2bf(a0) | ((unsigned int)f2bf(a1v)<<16);
        float uf; __builtin_memcpy(&uf,&u,4);
        ob[i2>>2][i2&3] = uf;
      }
      st8x16_sc(Ybf + m*512 + seg*64, ob);
      __syncthreads();
      if (tid == 0)
        __hip_atomic_store(&cctrs[w*32], c+1, __ATOMIC_RELAXED, AGENT);
    }
  } else {
    // ================= VOCAB PROJECTION (128 WGs x 250 cols) =================
    const int w2 = blockIdx.x - 72;          // 0..127
    const int c0 = w2*250;
    const int cn = 250;
    for (int cc = tid; cc < cn; cc += 256){
      const float* pw = projWf + (long)(c0+cc)*512;
      float s2 = 0.f;
      for (int k=0;k<512;k++) s2 += lnb[k]*pw[k];
      s.v.s2g[cc] = s2;
    }
    for (int i = tid; i < 512; i += 256) s.v.gl[i] = lng[i];
    __syncthreads();
    const f4 z4 = {0.f,0.f,0.f,0.f};
    for (int c=0; c<16; c++){
      cwait(cctrs, c+1);
      for (int half=0; half<2; half++){
        const long rbase = (long)c*256 + half*128;
        {
          const int row = tid >> 1, seg = tid & 1;
          const unsigned short* src = Ybf + (rbase + row)*512 + seg*256;
          #pragma unroll
          for (int blk=0; blk<2; blk++){
            f4 av[16];
            const f4* asrc = (const f4*)(src + blk*128);
            #pragma unroll
            for (int i=0;i<16;i++) av[i] = asrc[i];
            #pragma unroll
            for (int i=0;i<16;i++){
              f4 tv = av[i];
              short8 s8; __builtin_memcpy(&s8, &tv, 16);
              st8(s.v.a_s, row, 512, seg*256 + blk*128 + i*8, s8);
            }
          }
        }
        __syncthreads();
        for (int nt=0; nt<4; nt++){
          f4 acc[8] = {z4,z4,z4,z4,z4,z4,z4,z4};
          for (int kt=0; kt<8; kt++){
            {
              const int r = tid >> 2, q = tid & 3, k0 = q*16;
              const int col = nt*64 + r;
              short8 v0 = {0,0,0,0,0,0,0,0}, v1 = {0,0,0,0,0,0,0,0};
              if (col < cn){
                const unsigned short* src = Pbf + (long)(c0+col)*512 + kt*64 + k0;
                #pragma unroll
                for (int i=0;i<8;i++){
                  v0[i] = (short)f2bf(bf2f(src[i])   * s.v.gl[kt*64 + k0 + i]);
                  v1[i] = (short)f2bf(bf2f(src[8+i]) * s.v.gl[kt*64 + k0 + 8 + i]);
                }
              }
              st8(s.v.b_s, r, 64, k0, v0);
              st8(s.v.b_s, r, 64, k0+8, v1);
            }
            __syncthreads();
            #pragma unroll
            for (int kf=0; kf<2; kf++){
              short8 bfr = ldfrag(s.v.b_s, wv*16, 64, kf*32);
              #pragma unroll
              for (int mt=0; mt<8; mt++){
                short8 afr = ldfrag(s.v.a_s, mt*16, 512, kt*64 + kf*32);
                acc[mt] = __builtin_amdgcn_mfma_f32_16x16x32_bf16(afr, bfr, acc[mt], 0,0,0);
              }
            }
            __syncthreads();
          }
          const int colloc = nt*64 + wv*16 + (lane & 15);
          if (colloc < cn){
            const int vcol = c0 + colloc;
            const float corr = s.v.s2g[colloc] + projB[vcol];
            #pragma unroll
            for (int mt=0; mt<8; mt++){
              #pragma unroll
              for (int rr=0; rr<4; rr++){
                int rowl = mt*16 + (lane>>4)*4 + rr;
                long m = rbase + rowl;
                long tt = m >> 5, b = m & 31;
                out[(b*128 + tt)*32000 + vcol] = acc[mt][rr] + corr;
              }
            }
          }
        }
        __syncthreads();
      }
    }
  }
}

extern "C" void kernel_launch(void* const* d_in, const int* in_sizes, int n_in,
                              void* d_out, int out_size, void* d_ws, size_t ws_size,
                              hipStream_t stream)
{
  const int* nx = (const int*)d_in[0];
  const int* x = (const int*)d_in[1];
  const int* label = (const int*)d_in[2];
  const float* tok = (const float*)d_in[3];
  const float* start = (const float*)d_in[4];
  const float* style = (const float*)d_in[5];
  const float* eWihF = (const float*)d_in[6];
  const float* eWhhF = (const float*)d_in[7];
  const float* ebihF = (const float*)d_in[8];
  const float* ebhhF = (const float*)d_in[9];
  const float* eWihB = (const float*)d_in[10];
  const float* eWhhB = (const float*)d_in[11];
  const float* ebihB = (const float*)d_in[12];
  const float* ebhhB = (const float*)d_in[13];
  const float* dWih = (const float*)d_in[14];
  const float* dWhh = (const float*)d_in[15];
  const float* dbih = (const float*)d_in[16];
  const float* dbhh = (const float*)d_in[17];
  const float* ainW = (const float*)d_in[18];
  const float* ainB = (const float*)d_in[19];
  const float* aoutW = (const float*)d_in[20];
  const float* aoutB = (const float*)d_in[21];
  const float* lng = (const float*)d_in[22];
  const float* lnb = (const float*)d_in[23];
  const float* projW = (const float*)d_in[24];
  const float* projB = (const float*)d_in[25];
  float* out = (float*)d_out;
  char* W = (char*)d_ws;

  size_t off = 0;
  auto alloc = [&](size_t sz){ size_t o = off; off = (off + sz + 255) & ~(size_t)255; return o; };
  const size_t O_HF   = alloc(4*32*256*4);      // fp32 encoder h ping-pong (zeroed)
  const size_t O_BAR  = alloc(16384);           // dec lines [0,8192) | conv lines [8192,9216) | enc slots [12288,13312)
  const size_t O_EIHF = alloc(768*128*2);
  const size_t O_EIHB = alloc(768*128*2);
  const size_t O_DIH  = alloc(1536*128*2);
  const size_t O_AIN  = alloc(1536*512*2);
  const size_t O_AOUT = alloc(512*512*2);
  const size_t O_PROJ = alloc((size_t)32000*512*2);
  const size_t O_EMBE = alloc(4096*128*2);
  const size_t O_EMBD = alloc(4096*128*2);
  const size_t O_KBF  = alloc((size_t)32*8*128*64*2);
  const size_t O_VBF  = alloc((size_t)32*8*128*64*2);
  const size_t O_HDEC = alloc(32*256*4);
  const size_t O_YBF  = alloc((size_t)4096*512*2);
  const size_t O_GIF  = alloc((size_t)4096*768*4);
  const size_t O_GIB  = alloc((size_t)4096*768*4);
  const size_t O_GID  = alloc((size_t)4096*1536*4);
  const size_t O_OUTF = alloc((size_t)4096*256*4);
  const size_t O_OUTB = alloc((size_t)4096*256*4);
  const size_t O_KVP  = alloc((size_t)4096*1024*4);
  const size_t O_Y    = alloc((size_t)4096*512*4);
  const size_t O_H0   = alloc(32*512*4);

  (void)hipMemsetAsync(W + O_HF, 0, (O_BAR - O_HF) + 16384, stream);

  auto US = [&](size_t o){ return (unsigned short*)(W + o); };
  auto FP = [&](size_t o){ return (float*)(W + o); };

  {
    const struct { const float* s; size_t d; int n; } cvs[] = {
      {eWihF, O_EIHF, 768*128}, {eWihB, O_EIHB, 768*128},
      {dWih,  O_DIH,  1536*128},
      {ainW,  O_AIN,  1536*512}, {aoutW, O_AOUT, 512*512},
      {projW, O_PROJ, 32000*512},
    };
    for (auto &c : cvs){
      int n4 = c.n/4;
      int blocks = (n4 + 255)/256; if (blocks > 4096) blocks = 4096;
      cvt_kernel<<<blocks, 256, 0, stream>>>(c.s, US(c.d), n4);
    }
  }
  embed_kernel<<<1040, 256, 0, stream>>>(nx, x, label, tok, start, style,
                                         US(O_EMBE), US(O_EMBD), FP(O_H0));
  gemm64<0><<<dim3(64,12), 256, 0, stream>>>(US(O_EIHF), ebihF, FP(O_GIF), 4096, 768, 128, 768,
                                             US(O_EMBE), nullptr, nullptr);
  gemm64<0><<<dim3(64,12), 256, 0, stream>>>(US(O_EIHB), ebihB, FP(O_GIB), 4096, 768, 128, 768,
                                             US(O_EMBE), nullptr, nullptr);
  gemm64<0><<<dim3(64,24), 256, 0, stream>>>(US(O_DIH), dbih, FP(O_GID), 4096, 1536, 128, 1536,
                                             US(O_EMBD), nullptr, nullptr);
  enc_kernel<<<16, 384, 0, stream>>>(eWhhF, eWhhB, FP(O_GIF), FP(O_GIB),
                                     ebhhF, ebhhB, FP(O_OUTF), FP(O_OUTB), FP(O_HF),
                                     (int*)(W + O_BAR) + 3072);
  gemm64<1><<<dim3(64,16), 256, 0, stream>>>(US(O_AIN) + 512*512, ainB + 512, FP(O_KVP),
                                             4096, 1024, 512, 1024,
                                             nullptr, FP(O_OUTF), FP(O_OUTB));
  kv_reshape<<<16384, 256, 0, stream>>>(FP(O_KVP), US(O_KBF), US(O_VBF));
  dec_fused<<<200, 256, 0, stream>>>(dWhh, US(O_AIN), US(O_AOUT), US(O_KBF), US(O_VBF),
                                     FP(O_GID), dbhh, ainB, aoutB, lng, lnb, FP(O_H0),
                                     FP(O_Y), (unsigned int*)(W + O_HDEC), US(O_YBF),
                                     US(O_PROJ), projW, projB, out,
                                     (int*)(W + O_BAR));
  (void)in_sizes; (void)n_in; (void)out_size; (void)ws_size;
}

// Round 13
// 3643.017 us; speedup vs baseline: 1.0543x; 1.0543x over previous
//
#include <hip/hip_runtime.h>
#include <math.h>

typedef float f4 __attribute__((ext_vector_type(4)));
typedef short short8 __attribute__((ext_vector_type(8)));
typedef unsigned short us4 __attribute__((ext_vector_type(4)));

#define DEV static __device__ __forceinline__
#define AGENT __HIP_MEMORY_SCOPE_AGENT

DEV float bf2f(unsigned short u){ unsigned int x=((unsigned int)u)<<16; float f; __builtin_memcpy(&f,&x,4); return f; }
DEV unsigned short f2bf(float f){ unsigned int x; __builtin_memcpy(&x,&f,4); return (unsigned short)((x + 0x7fffu + ((x>>16)&1u))>>16); }

struct bfpair { short hi, lo; };
DEV bfpair splitbf(float v){
  bfpair p;
  unsigned short h_ = f2bf(v);
  p.hi = (short)h_;
  p.lo = (short)f2bf(v - bf2f(h_));
  return p;
}

DEV unsigned long long ldA64(const void* p){
  return __hip_atomic_load((const unsigned long long*)p, __ATOMIC_RELAXED, AGENT);
}
DEV void stA64(void* p, unsigned long long v){
  __hip_atomic_store((unsigned long long*)p, v, __ATOMIC_RELAXED, AGENT);
}
DEV void f2of(unsigned long long q, float* f0, float* f1){
  unsigned int lo=(unsigned int)q, hi=(unsigned int)(q>>32);
  __builtin_memcpy(f0,&lo,4); __builtin_memcpy(f1,&hi,4);
}
DEV unsigned long long packf2(float a, float b){
  unsigned int ua, ub; __builtin_memcpy(&ua,&a,4); __builtin_memcpy(&ub,&b,4);
  return (unsigned long long)ua | ((unsigned long long)ub << 32);
}

// ---- wide device-coherent loads/stores (bypass L2, coalesced 16B requests) ----
DEV void ld1x16_sc(const void* p, f4* o){
  asm volatile(
    "global_load_dwordx4 %0, %1, off sc0 sc1\n\t"
    "s_waitcnt vmcnt(0)"
    : "=&v"(o[0]) : "v"(p) : "memory");
}
DEV void ld8x16_sc(const void* p, f4* o){
  asm volatile(
    "global_load_dwordx4 %0, %8, off sc0 sc1\n\t"
    "global_load_dwordx4 %1, %8, off offset:16 sc0 sc1\n\t"
    "global_load_dwordx4 %2, %8, off offset:32 sc0 sc1\n\t"
    "global_load_dwordx4 %3, %8, off offset:48 sc0 sc1\n\t"
    "global_load_dwordx4 %4, %8, off offset:64 sc0 sc1\n\t"
    "global_load_dwordx4 %5, %8, off offset:80 sc0 sc1\n\t"
    "global_load_dwordx4 %6, %8, off offset:96 sc0 sc1\n\t"
    "global_load_dwordx4 %7, %8, off offset:112 sc0 sc1\n\t"
    "s_waitcnt vmcnt(0)"
    : "=&v"(o[0]),"=&v"(o[1]),"=&v"(o[2]),"=&v"(o[3]),
      "=&v"(o[4]),"=&v"(o[5]),"=&v"(o[6]),"=&v"(o[7])
    : "v"(p) : "memory");
}
DEV void ld16x16_sc(const void* p, f4* o){
  asm volatile(
    "global_load_dwordx4 %0, %16, off sc0 sc1\n\t"
    "global_load_dwordx4 %1, %16, off offset:16 sc0 sc1\n\t"
    "global_load_dwordx4 %2, %16, off offset:32 sc0 sc1\n\t"
    "global_load_dwordx4 %3, %16, off offset:48 sc0 sc1\n\t"
    "global_load_dwordx4 %4, %16, off offset:64 sc0 sc1\n\t"
    "global_load_dwordx4 %5, %16, off offset:80 sc0 sc1\n\t"
    "global_load_dwordx4 %6, %16, off offset:96 sc0 sc1\n\t"
    "global_load_dwordx4 %7, %16, off offset:112 sc0 sc1\n\t"
    "global_load_dwordx4 %8, %16, off offset:128 sc0 sc1\n\t"
    "global_load_dwordx4 %9, %16, off offset:144 sc0 sc1\n\t"
    "global_load_dwordx4 %10, %16, off offset:160 sc0 sc1\n\t"
    "global_load_dwordx4 %11, %16, off offset:176 sc0 sc1\n\t"
    "global_load_dwordx4 %12, %16, off offset:192 sc0 sc1\n\t"
    "global_load_dwordx4 %13, %16, off offset:208 sc0 sc1\n\t"
    "global_load_dwordx4 %14, %16, off offset:224 sc0 sc1\n\t"
    "global_load_dwordx4 %15, %16, off offset:240 sc0 sc1\n\t"
    "s_waitcnt vmcnt(0)"
    : "=&v"(o[0]),"=&v"(o[1]),"=&v"(o[2]),"=&v"(o[3]),
      "=&v"(o[4]),"=&v"(o[5]),"=&v"(o[6]),"=&v"(o[7]),
      "=&v"(o[8]),"=&v"(o[9]),"=&v"(o[10]),"=&v"(o[11]),
      "=&v"(o[12]),"=&v"(o[13]),"=&v"(o[14]),"=&v"(o[15])
    : "v"(p) : "memory");
}
DEV void st8x16_sc(void* p, const f4* v){
  asm volatile(
    "global_store_dwordx4 %8, %0, off sc0 sc1\n\t"
    "global_store_dwordx4 %8, %1, off offset:16 sc0 sc1\n\t"
    "global_store_dwordx4 %8, %2, off offset:32 sc0 sc1\n\t"
    "global_store_dwordx4 %8, %3, off offset:48 sc0 sc1\n\t"
    "global_store_dwordx4 %8, %4, off offset:64 sc0 sc1\n\t"
    "global_store_dwordx4 %8, %5, off offset:80 sc0 sc1\n\t"
    "global_store_dwordx4 %8, %6, off offset:96 sc0 sc1\n\t"
    "global_store_dwordx4 %8, %7, off offset:112 sc0 sc1\n\t"
    "s_waitcnt vmcnt(0)"
    :: "v"(v[0]),"v"(v[1]),"v"(v[2]),"v"(v[3]),
       "v"(v[4]),"v"(v[5]),"v"(v[6]),"v"(v[7]),"v"(p) : "memory");
}

// LDS addressing with XOR swizzle on 16B chunks
DEV int lds_off(int row,int strideShorts,int kShort){
  return row*strideShorts*2 + ((((kShort & ~7)*2) ^ ((row & 7)<<4)) + (kShort & 7)*2);
}
DEV void st8(unsigned short* lds,int row,int strideShorts,int k0,short8 v){
  *(short8*)((char*)lds + lds_off(row,strideShorts,k0)) = v;
}
DEV short8 ldfrag(const unsigned short* lds,int rowBase,int strideShorts,int k0){
  int lane = (int)(threadIdx.x & 63u);
  int row = rowBase + (lane & 15);
  int k = k0 + (lane >> 4)*8;
  return *(const short8*)((const char*)lds + lds_off(row,strideShorts,k));
}

DEV float dot8(f4 a0, f4 a1, short8 w){
  return a0[0]*bf2f((unsigned short)w[0]) + a0[1]*bf2f((unsigned short)w[1])
       + a0[2]*bf2f((unsigned short)w[2]) + a0[3]*bf2f((unsigned short)w[3])
       + a1[0]*bf2f((unsigned short)w[4]) + a1[1]*bf2f((unsigned short)w[5])
       + a1[2]*bf2f((unsigned short)w[6]) + a1[3]*bf2f((unsigned short)w[7]);
}

// enc barrier: slot-per-generation (8 WGs, low contention)
DEV void gbar_slot(int* slot, int nwg){
  __syncthreads();
  if (threadIdx.x==0){
    __hip_atomic_fetch_add(slot,1,__ATOMIC_RELAXED,AGENT);
    while (__hip_atomic_load(slot,__ATOMIC_RELAXED,AGENT) < nwg){
      __builtin_amdgcn_s_sleep(2);
    }
  }
  __syncthreads();
}

// dec barrier: per-WG counters on separate cachelines
DEV void dbar(int* ctrs, int wg, int target){
  __syncthreads();
  if (threadIdx.x < 64){
    if (threadIdx.x == 0)
      __hip_atomic_store(&ctrs[wg*32], target, __ATOMIC_RELAXED, AGENT);
    for(;;){
      int v = __hip_atomic_load(&ctrs[(int)threadIdx.x*32], __ATOMIC_RELAXED, AGENT);
      if (__all(v >= target)) break;
      __builtin_amdgcn_s_sleep(2);
    }
  }
  __syncthreads();
}
DEV void vwait(int* ctrs, int target){
  if (threadIdx.x < 64){
    for(;;){
      int v = __hip_atomic_load(&ctrs[(int)threadIdx.x*32], __ATOMIC_RELAXED, AGENT);
      if (__all(v >= target)) break;
      __builtin_amdgcn_s_sleep(64);
    }
  }
  __syncthreads();
}
DEV void cwait(int* cctrs, int target){
  if (threadIdx.x < 64){
    for(;;){
      int v = __hip_atomic_load(&cctrs[((int)threadIdx.x & 7)*32], __ATOMIC_RELAXED, AGENT);
      if (__all(v >= target)) break;
      __builtin_amdgcn_s_sleep(64);
    }
  }
  __syncthreads();
}

__global__ void cvt_kernel(const float* __restrict__ src, unsigned short* __restrict__ dst, int n4){
  int stride = gridDim.x*blockDim.x;
  for (long i = blockIdx.x*blockDim.x + threadIdx.x; i < n4; i += stride){
    f4 v = *(const f4*)(src + i*4);
    us4 o; o[0]=f2bf(v[0]); o[1]=f2bf(v[1]); o[2]=f2bf(v[2]); o[3]=f2bf(v[3]);
    *(us4*)(dst + i*4) = o;
  }
}

__global__ void embed_kernel(const int* __restrict__ nx, const int* __restrict__ x,
  const int* __restrict__ label, const float* __restrict__ tok,
  const float* __restrict__ start, const float* __restrict__ style,
  unsigned short* __restrict__ embE, unsigned short* __restrict__ embD,
  float* __restrict__ h0)
{
  const int half = 4096*32;
  int i = blockIdx.x*256 + threadIdx.x;
  if (i < 2*half){
    const bool dec = i >= half;
    int j = dec ? i - half : i;
    int m = j >> 5, c4 = j & 31;
    int b = m & 31, tt = m >> 5;
    const float* src;
    if (!dec) src = tok + (long)nx[b*128 + tt]*128;
    else src = (tt == 0) ? start : (tok + (long)x[b*128 + tt - 1]*128);
    f4 v = *(const f4*)(src + c4*4);
    us4 o; o[0]=f2bf(v[0]); o[1]=f2bf(v[1]); o[2]=f2bf(v[2]); o[3]=f2bf(v[3]);
    *(us4*)((dec ? embD : embE) + (long)m*128 + c4*4) = o;
  } else {
    int j = i - 2*half;
    if (j < 4096){
      int b = j >> 7, c4 = j & 127;
      *(f4*)(h0 + b*512 + c4*4) = *(const f4*)(style + (long)label[b]*512 + c4*4);
    }
  }
}

__global__ void kv_reshape(const float* __restrict__ kvp, unsigned short* __restrict__ Kb, unsigned short* __restrict__ Vb){
  long i = (long)blockIdx.x*256 + threadIdx.x;
  if (i >= (long)4096*1024) return;
  int m = (int)(i >> 10), n = (int)(i & 1023);
  int s = m >> 5, b = m & 31;
  unsigned short bv = f2bf(kvp[i]);
  if (n < 512){
    int hh = n >> 6, d = n & 63;
    Kb[((long)(b*8 + hh)*128 + s)*64 + d] = bv;
  } else {
    int n2 = n - 512; int hh = n2 >> 6, d = n2 & 63;
    Vb[((long)(b*8 + hh)*64 + d)*128 + s] = bv;
  }
}

// Generic 64x64 bf16-MFMA GEMM (MODE 0: A bf16; MODE 1: A=concat f32 K=512)
template<int MODE>
__global__ __launch_bounds__(256,2) void gemm64(
  const unsigned short* __restrict__ Bw, const float* __restrict__ bias,
  float* __restrict__ C, int M, int N, int K, int ldC,
  const unsigned short* __restrict__ Abf,
  const float* __restrict__ Af0, const float* __restrict__ Af1)
{
  __shared__ unsigned short a_s[64*64];
  __shared__ unsigned short b_s[64*64];
  const int tid = threadIdx.x, lane = tid & 63, wv = tid >> 6;
  const long mb = (long)blockIdx.x*64, nb = (long)blockIdx.y*64;
  f4 z = {0.f,0.f,0.f,0.f};
  f4 acc[4] = {z,z,z,z};
  const int r = tid >> 2, q = tid & 3, k0 = q*16;
  for (int kb = 0; kb < K; kb += 64){
    if (MODE==0){
      const unsigned short* src = Abf + (mb + r)*K + kb + k0;
      st8(a_s, r, 64, k0,   *(const short8*)src);
      st8(a_s, r, 64, k0+8, *(const short8*)(src+8));
    } else {
      float tmp[16];
      long m = mb + r;
      int kg = kb + k0;
      const float* base = (kg < 256) ? (Af0 + m*256 + kg) : (Af1 + m*256 + (kg - 256));
      #pragma unroll
      for (int i=0;i<16;i++) tmp[i] = base[i];
      short8 v0, v1;
      #pragma unroll
      for (int i=0;i<8;i++){ v0[i] = (short)f2bf(tmp[i]); v1[i] = (short)f2bf(tmp[8+i]); }
      st8(a_s, r, 64, k0, v0); st8(a_s, r, 64, k0+8, v1);
    }
    {
      const unsigned short* src = Bw + (nb + r)*K + kb + k0;
      st8(b_s, r, 64, k0,   *(const short8*)src);
      st8(b_s, r, 64, k0+8, *(const short8*)(src+8));
    }
    __syncthreads();
    #pragma unroll
    for (int kf=0; kf<2; kf++){
      short8 bfr = ldfrag(b_s, wv*16, 64, kf*32);
      #pragma unroll
      for (int mt=0; mt<4; mt++){
        short8 afr = ldfrag(a_s, mt*16, 64, kf*32);
        acc[mt] = __builtin_amdgcn_mfma_f32_16x16x32_bf16(afr, bfr, acc[mt], 0,0,0);
      }
    }
    __syncthreads();
  }
  const long col = nb + wv*16 + (lane & 15);
  const float bs = bias[col];
  #pragma unroll
  for (int mt=0; mt<4; mt++){
    #pragma unroll
    for (int rr=0; rr<4; rr++){
      long row = mb + mt*16 + (lane>>4)*4 + rr;
      C[row*(long)ldC + col] = acc[mt][rr] + bs;
    }
  }
}

// Bidirectional GRU encoder — wide sc loads for h stage-in, packed 8B h ping-pong
__global__ __launch_bounds__(384) void enc_kernel(
  const float* __restrict__ WhhF_f, const float* __restrict__ WhhB_f,
  const float* __restrict__ GIF, const float* __restrict__ GIB,
  const float* __restrict__ bhhF, const float* __restrict__ bhhB,
  float* __restrict__ OUTF, float* __restrict__ OUTB,
  float* __restrict__ Hf,
  int* bar)
{
  __shared__ unsigned short whh_hi[96*256];
  __shared__ unsigned short whh_lo[96*256];
  __shared__ unsigned short a_hi[32*256];
  __shared__ unsigned short a_lo[32*256];
  __shared__ float ghscr[32*96];
  const int tid = threadIdx.x;
  const int wg = blockIdx.x;
  const int dir = wg >> 3, wgl = wg & 7;
  const float* Whh_f = dir ? WhhB_f : WhhF_f;
  const float* GI = dir ? GIB : GIF;
  const float* bhh = dir ? bhhB : bhhF;
  float* OUT = dir ? OUTB : OUTF;

  for (int idx = tid; idx < 96*32; idx += 384){
    int lr = idx >> 5, ch = idx & 31;
    int g_ = lr >> 5, jj = lr & 31;
    const float* wsrc = Whh_f + (long)(g_*256 + wgl*32 + jj)*256 + ch*8;
    short8 vh, vl;
    #pragma unroll
    for (int i=0;i<8;i++){ bfpair p = splitbf(wsrc[i]); vh[i] = p.hi; vl[i] = p.lo; }
    st8(whh_hi, lr, 256, ch*8, vh);
    st8(whh_lo, lr, 256, ch*8, vl);
  }
  __syncthreads();
  for (int t = 0; t < 128; t++){
    const int s = dir ? (127 - t) : t;
    const float* hbr = Hf + ((size_t)((t&1)*2 + dir))*(32*256);
    float* hbw = Hf + ((size_t)(((t+1)&1)*2 + dir))*(32*256);
    if (tid < 256){
      int b = tid >> 3, kg = tid & 7;
      f4 hv[8];
      ld8x16_sc(hbr + b*256 + kg*32, hv);
      #pragma unroll
      for (int c=0;c<4;c++){
        short8 vh, vl;
        #pragma unroll
        for (int e=0;e<8;e++){
          float f = hv[c*2 + (e>>2)][e&3];
          bfpair p = splitbf(f);
          vh[e] = p.hi; vl[e] = p.lo;
        }
        st8(a_hi, b, 256, kg*32 + c*8, vh);
        st8(a_lo, b, 256, kg*32 + c*8, vl);
      }
    }
    __syncthreads();
    {
      const int wv = tid >> 6;
      f4 acc0 = {0.f,0.f,0.f,0.f}, acc1 = {0.f,0.f,0.f,0.f};
      #pragma unroll
      for (int kf=0; kf<8; kf++){
        short8 bhi = ldfrag(whh_hi, wv*16, 256, kf*32);
        short8 blo = ldfrag(whh_lo, wv*16, 256, kf*32);
        short8 ah0 = ldfrag(a_hi, 0, 256, kf*32);
        short8 al0 = ldfrag(a_lo, 0, 256, kf*32);
        short8 ah1 = ldfrag(a_hi, 16, 256, kf*32);
        short8 al1 = ldfrag(a_lo, 16, 256, kf*32);
        acc0 = __builtin_amdgcn_mfma_f32_16x16x32_bf16(ah0, bhi, acc0, 0,0,0);
        acc0 = __builtin_amdgcn_mfma_f32_16x16x32_bf16(al0, bhi, acc0, 0,0,0);
        acc0 = __builtin_amdgcn_mfma_f32_16x16x32_bf16(ah0, blo, acc0, 0,0,0);
        acc1 = __builtin_amdgcn_mfma_f32_16x16x32_bf16(ah1, bhi, acc1, 0,0,0);
        acc1 = __builtin_amdgcn_mfma_f32_16x16x32_bf16(al1, bhi, acc1, 0,0,0);
        acc1 = __builtin_amdgcn_mfma_f32_16x16x32_bf16(ah1, blo, acc1, 0,0,0);
      }
      const int lane = tid & 63;
      const int cl = wv*16 + (lane & 15);
      #pragma unroll
      for (int rr=0; rr<4; rr++){
        int r0 = (lane>>4)*4 + rr;
        ghscr[r0*96 + cl] = acc0[rr];
        ghscr[(16+r0)*96 + cl] = acc1[rr];
      }
    }
    __syncthreads();
    for (int task = tid; task < 512; task += 384){
      int b = task >> 4, pj = task & 15;
      int jj0 = pj*2;
      int jg0 = wgl*32 + jj0;
      const float* gi = GI + ((long)s*32 + b)*768;
      unsigned long long hq = ldA64(hbr + b*256 + jg0);
      float hp0, hp1; f2of(hq, &hp0, &hp1);
      float hn01[2];
      #pragma unroll
      for (int e=0;e<2;e++){
        int jj = jj0 + e, jg = jg0 + e;
        float ghr = ghscr[b*96 + jj]      + bhh[jg];
        float ghz = ghscr[b*96 + 32 + jj] + bhh[256 + jg];
        float ghn = ghscr[b*96 + 64 + jj] + bhh[512 + jg];
        float r_ = 1.f/(1.f + __expf(-(gi[jg] + ghr)));
        float z_ = 1.f/(1.f + __expf(-(gi[256+jg] + ghz)));
        float n_ = tanhf(gi[512+jg] + r_*ghn);
        float hp = e ? hp1 : hp0;
        hn01[e] = (1.f - z_)*n_ + z_*hp;
      }
      *(unsigned long long*)(&OUT[((long)s*32 + b)*256 + jg0]) = packf2(hn01[0], hn01[1]);
      stA64(hbw + b*256 + jg0, packf2(hn01[0], hn01[1]));
    }
    gbar_slot(bar + dir*128 + t, 8);
  }
}

// ---------------- fused decoder + converters + vocab-projection ----------------
struct DecS {
  unsigned short whh_hi[32*512];
  unsigned short whh_lo[32*512];
  unsigned short a_hi[32*512];
  unsigned short a_lo[32*512];
  float scr[32*64];
  float attn_l[4*128];
  float ctxs[4*64];
  float hnfr[32*8];
  float lngl[512], lnbl[512];
  float s1l[24], s2l[24];
};
struct VocS {
  unsigned short a_s[128*512];
  unsigned short b_s[64*64];
  float gl[512];
  float s2g[256];
};
struct CvtS {
  float redm[32*8*2];
  float murs[64];
};
union SU { DecS d; VocS v; CvtS c; };

__global__ __launch_bounds__(256,1) void dec_fused(
  const float* __restrict__ Whh_f,
  const unsigned short* __restrict__ WqBf,
  const unsigned short* __restrict__ Wout,
  const unsigned short* __restrict__ Kbf,
  const unsigned short* __restrict__ Vbf,
  const float* __restrict__ GI,
  const float* __restrict__ bhh,
  const float* __restrict__ aib,
  const float* __restrict__ aob,
  const float* __restrict__ lng,
  const float* __restrict__ lnb,
  const float* __restrict__ h0,
  float* __restrict__ Y,
  unsigned int* __restrict__ hdec32,
  unsigned short* __restrict__ Ybf,
  const unsigned short* __restrict__ Pbf,
  const float* __restrict__ projWf,
  const float* __restrict__ projB,
  float* __restrict__ out,
  int* ctrs)
{
  __shared__ SU s;
  const int tid = threadIdx.x;
  const int lane = tid & 63, wv = tid >> 6;
  int* cctrs = ctrs + 2048;   // converter lines: bytes [8192, 9216)

  if (blockIdx.x < 64){
    // ================= DECODER =================
    const int wg = blockIdx.x;
    const int h = wg >> 3, bg = wg & 7;
    const int jbase = wg*8;
    const int cw = wg & 7;

    if (tid < 24){ s.d.s1l[tid] = 0.f; s.d.s2l[tid] = 0.f; }
    __syncthreads();
    for (int idx = tid; idx < 32*64; idx += 256){
      int lr = idx >> 6, ch = idx & 63;
      short8 vh = {0,0,0,0,0,0,0,0}, vl = {0,0,0,0,0,0,0,0};
      if (lr < 24){
        int g_ = lr >> 3, jj = lr & 7;
        const float* wsrc = Whh_f + (long)(g_*512 + jbase + jj)*512 + ch*8;
        float s1p = 0.f, s2p = 0.f;
        #pragma unroll
        for (int i=0;i<8;i++){
          float wvv = wsrc[i];
          float gv = lng[ch*8+i];
          float bv = lnb[ch*8+i];
          float wp = wvv*gv;
          bfpair p = splitbf(wp);
          vh[i] = p.hi; vl[i] = p.lo;
          s1p += wp; s2p += bv*wvv;
        }
        atomicAdd(&s.d.s1l[lr], s1p);
        atomicAdd(&s.d.s2l[lr], s2p);
      }
      st8(s.d.whh_hi, lr, 512, ch*8, vh);
      st8(s.d.whh_lo, lr, 512, ch*8, vl);
    }
    for (int i = tid; i < 512; i += 256){ s.d.lngl[i] = lng[i]; s.d.lnbl[i] = lnb[i]; }

    const int qrow = h*64 + wv*16 + (lane & 15);
    const int kb0q = (lane>>4)*8;
    const unsigned short* wqbase = WqBf + (long)qrow*512 + kb0q;
    const int b_l = wv;
    const int bglob = bg*4 + b_l;
    const unsigned short* kbase = Kbf + ((long)(bglob*8 + h)*128 + lane*2)*64;
    const unsigned short* vbase = Vbf + ((long)(bglob*8 + h)*64 + lane)*128;
    const int jp = tid & 127;
    const unsigned short* wobase = Wout + (long)(jp*4)*512 + h*64;
    const float qb = aib[h*64 + wv*16 + (lane & 15)];
    const int bA = tid >> 3, kgA = tid & 7;
    const int jjA = tid & 7;
    const int jgA = jbase + jjA;
    const float bhr = bhh[jgA], bhz = bhh[512 + jgA], bhn = bhh[1024 + jgA];
    const float aobv = aob[jgA];
    __syncthreads();

    int lgen = 0;
    float gir = GI[((long)0*32 + bA)*1536 + jgA];
    float giz = GI[((long)0*32 + bA)*1536 + 512 + jgA];
    float gin = GI[((long)0*32 + bA)*1536 + 1024 + jgA];
    for (int t = 0; t < 128; t++){
      // ---- STAGE A: raw-y sc read + LDS staging; stats via 8-lane shfl (register mu/rsv) ----
      float mu_r = 0.f, rsv_r = 1.f;
      if (t == 0){
        const float* src = h0 + bA*512 + kgA*64;
        #pragma unroll
        for (int c=0;c<8;c++){
          short8 vh, vl;
          #pragma unroll
          for (int i=0;i<8;i++){
            float v = src[c*8+i];
            float gv = s.d.lngl[kgA*64 + c*8 + i];
            bfpair p = splitbf(v/gv);
            vh[i] = p.hi; vl[i] = p.lo;
            if (kgA == h && c == cw) s.d.hnfr[bA*8+i] = v;
          }
          st8(s.d.a_hi, bA, 512, kgA*64 + c*8, vh);
          st8(s.d.a_lo, bA, 512, kgA*64 + c*8, vl);
        }
      } else {
        f4 yv[16];
        ld16x16_sc(Y + ((long)(t-1)*32 + bA)*512 + kgA*64, yv);
        float sm = 0.f, sq = 0.f;
        #pragma unroll
        for (int c=0;c<8;c++){
          short8 vh, vl;
          #pragma unroll
          for (int e=0;e<8;e++){
            float f = yv[c*2 + (e>>2)][e&3];
            sm += f; sq += f*f;
            bfpair p = splitbf(f);
            vh[e] = p.hi; vl[e] = p.lo;
            if (kgA == h && c == cw) s.d.hnfr[bA*8+e] = f;
          }
          st8(s.d.a_hi, bA, 512, kgA*64 + c*8, vh);
          st8(s.d.a_lo, bA, 512, kgA*64 + c*8, vl);
        }
        // batch bA's 8 threads are 8 contiguous lanes: reduce in-wave, keep stats in registers
        #pragma unroll
        for (int o=1;o<8;o<<=1){ sm += __shfl_xor(sm, o); sq += __shfl_xor(sq, o); }
        mu_r = sm*(1.f/512.f);
        float var = sq*(1.f/512.f) - mu_r*mu_r;
        rsv_r = rsqrtf(var + 1e-5f);
      }
      __syncthreads();
      {
        const int mt = wv >> 1, nt = wv & 1;
        f4 acc = {0.f,0.f,0.f,0.f};
        #pragma unroll
        for (int kf=0; kf<16; kf++){
          short8 bhi = ldfrag(s.d.whh_hi, nt*16, 512, kf*32);
          short8 blo = ldfrag(s.d.whh_lo, nt*16, 512, kf*32);
          short8 ahi = ldfrag(s.d.a_hi, mt*16, 512, kf*32);
          short8 alo = ldfrag(s.d.a_lo, mt*16, 512, kf*32);
          acc = __builtin_amdgcn_mfma_f32_16x16x32_bf16(ahi, bhi, acc, 0,0,0);
          acc = __builtin_amdgcn_mfma_f32_16x16x32_bf16(alo, bhi, acc, 0,0,0);
          acc = __builtin_amdgcn_mfma_f32_16x16x32_bf16(ahi, blo, acc, 0,0,0);
        }
        const int cl = nt*16 + (lane & 15);
        if (cl < 24){
          #pragma unroll
          for (int rr=0; rr<4; rr++){
            int row = mt*16 + (lane>>4)*4 + rr;
            s.d.scr[row*32 + cl] = acc[rr];
          }
        }
      }
      __syncthreads();
      {
        const float mu = mu_r;
        const float rsv = rsv_r;
        const float c2 = rsv*mu;
        float ghr = rsv*s.d.scr[bA*32 + jjA]      - c2*s.d.s1l[jjA]      + (t ? s.d.s2l[jjA]      : 0.f) + bhr;
        float ghz = rsv*s.d.scr[bA*32 + 8 + jjA]  - c2*s.d.s1l[8 + jjA]  + (t ? s.d.s2l[8 + jjA]  : 0.f) + bhz;
        float ghn = rsv*s.d.scr[bA*32 + 16 + jjA] - c2*s.d.s1l[16 + jjA] + (t ? s.d.s2l[16 + jjA] : 0.f) + bhn;
        float r_ = 1.f/(1.f + __expf(-(gir + ghr)));
        float z_ = 1.f/(1.f + __expf(-(giz + ghz)));
        float n_ = tanhf(gin + r_*ghn);
        float hpv = s.d.hnfr[bA*8 + jjA];
        float hp = t ? (hpv - mu)*rsv*s.d.lngl[jgA] + s.d.lnbl[jgA] : hpv;
        float hd = (1.f - z_)*n_ + z_*hp;
        unsigned int hb = (unsigned int)f2bf(hd);
        unsigned int other = (unsigned int)__shfl_xor((int)hb, 1);
        if ((jjA & 1) == 0){
          unsigned int pack = hb | (other << 16);
          __hip_atomic_store(&hdec32[bA*256 + (jgA >> 1)], pack, __ATOMIC_RELAXED, AGENT);
        }
        __hip_atomic_store(&Y[((long)t*32 + bA)*512 + jgA], hd + aobv, __ATOMIC_RELAXED, AGENT);
      }
      dbar(ctrs, wg, ++lgen);
      // ---- STAGE B: stage only this WG's 4 batch rows of hdec ----
      {
        const int r4 = tid >> 6, ch = tid & 63;
        f4 hv;
        ld1x16_sc(hdec32 + (bg*4 + r4)*256 + ch*4, &hv);
        short8 v;
        #pragma unroll
        for (int w2=0; w2<4; w2++){
          float fv = hv[w2];
          unsigned int u; __builtin_memcpy(&u, &fv, 4);
          v[w2*2]   = (short)(u & 0xffff);
          v[w2*2+1] = (short)(u >> 16);
        }
        st8(s.d.a_hi, r4, 512, ch*8, v);
      }
      __syncthreads();
      {
        f4 acc0 = {0.f,0.f,0.f,0.f};
        #pragma unroll
        for (int kf=0; kf<16; kf++){
          short8 bfr = *(const short8*)(wqbase + kf*32);
          acc0 = __builtin_amdgcn_mfma_f32_16x16x32_bf16(ldfrag(s.d.a_hi, 0, 512, kf*32), bfr, acc0, 0,0,0);
        }
        const int cl = wv*16 + (lane & 15);
        if ((lane >> 4) == 0){
          #pragma unroll
          for (int rr=0; rr<4; rr++)
            s.d.scr[rr*64 + cl] = acc0[rr] + qb;
        }
      }
      __syncthreads();
      {
        const f4* qp = (const f4*)(s.d.scr + b_l*64);
        float s0 = 0.f, s1 = 0.f;
        #pragma unroll
        for (int c=0;c<8;c++) s0 += dot8(qp[c*2], qp[c*2+1], *(const short8*)(kbase + c*8));
        #pragma unroll
        for (int c=0;c<8;c++) s1 += dot8(qp[c*2], qp[c*2+1], *(const short8*)(kbase + 64 + c*8));
        s0 *= 0.125f; s1 *= 0.125f;
        float mx = fmaxf(s0, s1);
        #pragma unroll
        for (int o=1;o<64;o<<=1) mx = fmaxf(mx, __shfl_xor(mx, o));
        float e0 = __expf(s0 - mx), e1 = __expf(s1 - mx);
        float sm = e0 + e1;
        #pragma unroll
        for (int o=1;o<64;o<<=1) sm += __shfl_xor(sm, o);
        float inv = 1.f/sm;
        s.d.attn_l[b_l*128 + lane*2]   = e0*inv;
        s.d.attn_l[b_l*128 + lane*2+1] = e1*inv;
      }
      __syncthreads();
      {
        const f4* ap = (const f4*)(s.d.attn_l + b_l*128);
        float cx = 0.f;
        #pragma unroll
        for (int c=0;c<16;c++) cx += dot8(ap[c*2], ap[c*2+1], *(const short8*)(vbase + c*8));
        s.d.ctxs[b_l*64 + lane] = cx;
      }
      __syncthreads();
      {
        const int b2 = tid >> 7;
        #pragma unroll
        for (int jj=0;jj<4;jj++){
          const unsigned short* wb = wobase + (long)jj*512;
          short8 w0 = *(const short8*)(wb);
          short8 w1 = *(const short8*)(wb+8);
          short8 w2 = *(const short8*)(wb+16);
          short8 w3 = *(const short8*)(wb+24);
          short8 w4 = *(const short8*)(wb+32);
          short8 w5 = *(const short8*)(wb+40);
          short8 w6 = *(const short8*)(wb+48);
          short8 w7 = *(const short8*)(wb+56);
          #pragma unroll
          for (int bb=0; bb<2; bb++){
            const int bl = b2 + bb*2;
            const int bgl = bg*4 + bl;
            const f4* cp = (const f4*)(s.d.ctxs + bl*64);
            float cj = dot8(cp[0], cp[1], w0) + dot8(cp[2], cp[3], w1)
                     + dot8(cp[4], cp[5], w2) + dot8(cp[6], cp[7], w3)
                     + dot8(cp[8], cp[9], w4) + dot8(cp[10], cp[11], w5)
                     + dot8(cp[12], cp[13], w6) + dot8(cp[14], cp[15], w7);
            atomicAdd(&Y[((long)t*32 + bgl)*512 + jp*4 + jj], cj);
          }
        }
      }
      if (t < 127){
        long base = ((long)(t+1)*32 + bA)*1536 + jgA;
        gir = GI[base];
        giz = GI[base + 512];
        gin = GI[base + 1024];
      }
      dbar(ctrs, wg, ++lgen);
    }
  } else if (blockIdx.x < 72){
    // ================= CONVERTERS: Y chunk -> LN'd bf16 Ybf =================
    const int w = blockIdx.x - 64;
    const int rr = tid >> 3, seg = tid & 7;
    for (int c = 0; c < 16; c++){
      vwait(ctrs, 16*(c+1));
      long m = (long)c*256 + w*32 + rr;
      f4 yv[16];
      ld16x16_sc(Y + m*512 + seg*64, yv);
      float sm = 0.f, sq = 0.f;
      #pragma unroll
      for (int i=0;i<16;i++){
        f4 v = yv[i];
        sm += v[0]+v[1]+v[2]+v[3];
        sq += v[0]*v[0]+v[1]*v[1]+v[2]*v[2]+v[3]*v[3];
      }
      s.c.redm[(rr*8+seg)*2] = sm; s.c.redm[(rr*8+seg)*2+1] = sq;
      __syncthreads();
      if (tid < 32){
        float S1=0.f, S2=0.f;
        #pragma unroll
        for (int i=0;i<8;i++){ S1 += s.c.redm[(tid*8+i)*2]; S2 += s.c.redm[(tid*8+i)*2+1]; }
        float mu = S1*(1.f/512.f);
        float var = S2*(1.f/512.f) - mu*mu;
        s.c.murs[tid*2] = mu; s.c.murs[tid*2+1] = rsqrtf(var + 1e-5f);
      }
      __syncthreads();
      const float mu = s.c.murs[rr*2], rsv = s.c.murs[rr*2+1];
      f4 ob[8];
      #pragma unroll
      for (int i2=0;i2<32;i2++){
        float a0 = (yv[(2*i2)>>2][(2*i2)&3] - mu)*rsv;
        float a1v = (yv[(2*i2+1)>>2][(2*i2+1)&3] - mu)*rsv;
        unsigned int u = (unsigned int)f2bf(a0) | ((unsigned int)f2bf(a1v)<<16);
        float uf; __builtin_memcpy(&uf,&u,4);
        ob[i2>>2][i2&3] = uf;
      }
      st8x16_sc(Ybf + m*512 + seg*64, ob);
      __syncthreads();
      if (tid == 0)
        __hip_atomic_store(&cctrs[w*32], c+1, __ATOMIC_RELAXED, AGENT);
    }
  } else {
    // ================= VOCAB PROJECTION (128 WGs x 250 cols) =================
    const int w2 = blockIdx.x - 72;          // 0..127
    const int c0 = w2*250;
    const int cn = 250;
    for (int cc = tid; cc < cn; cc += 256){
      const float* pw = projWf + (long)(c0+cc)*512;
      float s2 = 0.f;
      for (int k=0;k<512;k++) s2 += lnb[k]*pw[k];
      s.v.s2g[cc] = s2;
    }
    for (int i = tid; i < 512; i += 256) s.v.gl[i] = lng[i];
    __syncthreads();
    const f4 z4 = {0.f,0.f,0.f,0.f};
    for (int c=0; c<16; c++){
      cwait(cctrs, c+1);
      for (int half=0; half<2; half++){
        const long rbase = (long)c*256 + half*128;
        {
          const int row = tid >> 1, seg = tid & 1;
          const unsigned short* src = Ybf + (rbase + row)*512 + seg*256;
          #pragma unroll
          for (int blk=0; blk<2; blk++){
            f4 av[16];
            ld16x16_sc(src + blk*128, av);
            #pragma unroll
            for (int i=0;i<16;i++){
              f4 tv = av[i];
              short8 s8; __builtin_memcpy(&s8, &tv, 16);
              st8(s.v.a_s, row, 512, seg*256 + blk*128 + i*8, s8);
            }
          }
        }
        __syncthreads();
        for (int nt=0; nt<4; nt++){
          f4 acc[8] = {z4,z4,z4,z4,z4,z4,z4,z4};
          for (int kt=0; kt<8; kt++){
            {
              const int r = tid >> 2, q = tid & 3, k0 = q*16;
              const int col = nt*64 + r;
              short8 v0 = {0,0,0,0,0,0,0,0}, v1 = {0,0,0,0,0,0,0,0};
              if (col < cn){
                const unsigned short* src = Pbf + (long)(c0+col)*512 + kt*64 + k0;
                #pragma unroll
                for (int i=0;i<8;i++){
                  v0[i] = (short)f2bf(bf2f(src[i])   * s.v.gl[kt*64 + k0 + i]);
                  v1[i] = (short)f2bf(bf2f(src[8+i]) * s.v.gl[kt*64 + k0 + 8 + i]);
                }
              }
              st8(s.v.b_s, r, 64, k0, v0);
              st8(s.v.b_s, r, 64, k0+8, v1);
            }
            __syncthreads();
            #pragma unroll
            for (int kf=0; kf<2; kf++){
              short8 bfr = ldfrag(s.v.b_s, wv*16, 64, kf*32);
              #pragma unroll
              for (int mt=0; mt<8; mt++){
                short8 afr = ldfrag(s.v.a_s, mt*16, 512, kt*64 + kf*32);
                acc[mt] = __builtin_amdgcn_mfma_f32_16x16x32_bf16(afr, bfr, acc[mt], 0,0,0);
              }
            }
            __syncthreads();
          }
          const int colloc = nt*64 + wv*16 + (lane & 15);
          if (colloc < cn){
            const int vcol = c0 + colloc;
            const float corr = s.v.s2g[colloc] + projB[vcol];
            #pragma unroll
            for (int mt=0; mt<8; mt++){
              #pragma unroll
              for (int rr=0; rr<4; rr++){
                int rowl = mt*16 + (lane>>4)*4 + rr;
                long m = rbase + rowl;
                long tt = m >> 5, b = m & 31;
                out[(b*128 + tt)*32000 + vcol] = acc[mt][rr] + corr;
              }
            }
          }
        }
        __syncthreads();
      }
    }
  }
}

extern "C" void kernel_launch(void* const* d_in, const int* in_sizes, int n_in,
                              void* d_out, int out_size, void* d_ws, size_t ws_size,
                              hipStream_t stream)
{
  const int* nx = (const int*)d_in[0];
  const int* x = (const int*)d_in[1];
  const int* label = (const int*)d_in[2];
  const float* tok = (const float*)d_in[3];
  const float* start = (const float*)d_in[4];
  const float* style = (const float*)d_in[5];
  const float* eWihF = (const float*)d_in[6];
  const float* eWhhF = (const float*)d_in[7];
  const float* ebihF = (const float*)d_in[8];
  const float* ebhhF = (const float*)d_in[9];
  const float* eWihB = (const float*)d_in[10];
  const float* eWhhB = (const float*)d_in[11];
  const float* ebihB = (const float*)d_in[12];
  const float* ebhhB = (const float*)d_in[13];
  const float* dWih = (const float*)d_in[14];
  const float* dWhh = (const float*)d_in[15];
  const float* dbih = (const float*)d_in[16];
  const float* dbhh = (const float*)d_in[17];
  const float* ainW = (const float*)d_in[18];
  const float* ainB = (const float*)d_in[19];
  const float* aoutW = (const float*)d_in[20];
  const float* aoutB = (const float*)d_in[21];
  const float* lng = (const float*)d_in[22];
  const float* lnb = (const float*)d_in[23];
  const float* projW = (const float*)d_in[24];
  const float* projB = (const float*)d_in[25];
  float* out = (float*)d_out;
  char* W = (char*)d_ws;

  size_t off = 0;
  auto alloc = [&](size_t sz){ size_t o = off; off = (off + sz + 255) & ~(size_t)255; return o; };
  const size_t O_HF   = alloc(4*32*256*4);      // fp32 encoder h ping-pong (zeroed)
  const size_t O_BAR  = alloc(16384);           // dec lines [0,8192) | conv lines [8192,9216) | enc slots [12288,13312)
  const size_t O_EIHF = alloc(768*128*2);
  const size_t O_EIHB = alloc(768*128*2);
  const size_t O_DIH  = alloc(1536*128*2);
  const size_t O_AIN  = alloc(1536*512*2);
  const size_t O_AOUT = alloc(512*512*2);
  const size_t O_PROJ = alloc((size_t)32000*512*2);
  const size_t O_EMBE = alloc(4096*128*2);
  const size_t O_EMBD = alloc(4096*128*2);
  const size_t O_KBF  = alloc((size_t)32*8*128*64*2);
  const size_t O_VBF  = alloc((size_t)32*8*128*64*2);
  const size_t O_HDEC = alloc(32*256*4);
  const size_t O_YBF  = alloc((size_t)4096*512*2);
  const size_t O_GIF  = alloc((size_t)4096*768*4);
  const size_t O_GIB  = alloc((size_t)4096*768*4);
  const size_t O_GID  = alloc((size_t)4096*1536*4);
  const size_t O_OUTF = alloc((size_t)4096*256*4);
  const size_t O_OUTB = alloc((size_t)4096*256*4);
  const size_t O_KVP  = alloc((size_t)4096*1024*4);
  const size_t O_Y    = alloc((size_t)4096*512*4);
  const size_t O_H0   = alloc(32*512*4);

  (void)hipMemsetAsync(W + O_HF, 0, (O_BAR - O_HF) + 16384, stream);

  auto US = [&](size_t o){ return (unsigned short*)(W + o); };
  auto FP = [&](size_t o){ return (float*)(W + o); };

  {
    const struct { const float* s; size_t d; int n; } cvs[] = {
      {eWihF, O_EIHF, 768*128}, {eWihB, O_EIHB, 768*128},
      {dWih,  O_DIH,  1536*128},
      {ainW,  O_AIN,  1536*512}, {aoutW, O_AOUT, 512*512},
      {projW, O_PROJ, 32000*512},
    };
    for (auto &c : cvs){
      int n4 = c.n/4;
      int blocks = (n4 + 255)/256; if (blocks > 4096) blocks = 4096;
      cvt_kernel<<<blocks, 256, 0, stream>>>(c.s, US(c.d), n4);
    }
  }
  embed_kernel<<<1040, 256, 0, stream>>>(nx, x, label, tok, start, style,
                                         US(O_EMBE), US(O_EMBD), FP(O_H0));
  gemm64<0><<<dim3(64,12), 256, 0, stream>>>(US(O_EIHF), ebihF, FP(O_GIF), 4096, 768, 128, 768,
                                             US(O_EMBE), nullptr, nullptr);
  gemm64<0><<<dim3(64,12), 256, 0, stream>>>(US(O_EIHB), ebihB, FP(O_GIB), 4096, 768, 128, 768,
                                             US(O_EMBE), nullptr, nullptr);
  gemm64<0><<<dim3(64,24), 256, 0, stream>>>(US(O_DIH), dbih, FP(O_GID), 4096, 1536, 128, 1536,
                                             US(O_EMBD), nullptr, nullptr);
  enc_kernel<<<16, 384, 0, stream>>>(eWhhF, eWhhB, FP(O_GIF), FP(O_GIB),
                                     ebhhF, ebhhB, FP(O_OUTF), FP(O_OUTB), FP(O_HF),
                                     (int*)(W + O_BAR) + 3072);
  gemm64<1><<<dim3(64,16), 256, 0, stream>>>(US(O_AIN) + 512*512, ainB + 512, FP(O_KVP),
                                             4096, 1024, 512, 1024,
                                             nullptr, FP(O_OUTF), FP(O_OUTB));
  kv_reshape<<<16384, 256, 0, stream>>>(FP(O_KVP), US(O_KBF), US(O_VBF));
  dec_fused<<<200, 256, 0, stream>>>(dWhh, US(O_AIN), US(O_AOUT), US(O_KBF), US(O_VBF),
                                     FP(O_GID), dbhh, ainB, aoutB, lng, lnb, FP(O_H0),
                                     FP(O_Y), (unsigned int*)(W + O_HDEC), US(O_YBF),
                                     US(O_PROJ), projW, projB, out,
                                     (int*)(W + O_BAR));
  (void)in_sizes; (void)n_in; (void)out_size; (void)ws_size;
}